// Round 5
// baseline (240.523 us; speedup 1.0000x reference)
//
#include <hip/hip_runtime.h>

// NMS3D: x (4,2,64,256,256) f32, 3x3x3 neighborhood-max excluding center,
// edge padding == index clamping.
//
// R9: register-deep streaming, no LDS, no barriers.
// Theory: all prior variants (reg-PF2 / LDS-PF2 / LDS-PF3) hold ~80-120 KB/CU
// in flight and all land at 83-88 us => concurrency-limited queuing
// equilibrium (~10 us loaded latency). LDS caps in-flight bytes at its
// 160 KB capacity; the 512 KB/CU VGPR file does not. This kernel keeps
// PF=3 slices x 6 rows in registers per wave, 12 independent waves/CU
// -> ~216 KB/CU in flight (2.4x all previous), zero synchronization.
//  - wave = 4 output rows; 6 row-loads/slice (1 row == one 64-lane float4
//    load); h-halo = register max across row-regs; w-halo = __shfl +-1.
//  - state per row compressed: m2 = max(vmax9[z-2], cross8[z-1]) folds two
//    arrays; + vm9p, vprev => 48 VGPR of state.
//  - 6 z-chunks of 11 (5x11+9=64), grid 768 = exactly 3 blocks/CU,
//    launch_bounds(256,3) caps VGPR at 170 (target ~160, no spill).
//  - fully unrolled (STEP macro): every array index static (no scratch).

constexpr int D_  = 64;
constexpr int H_  = 256;
constexpr int W_  = 256;
constexpr int HW_ = H_ * W_;
constexpr int DC  = 11;        // z-chunk size (last chunk emits 9)
constexpr int S   = DC + 2;    // 13 slices touched per chunk
constexpr int PF  = 3;         // register pipeline depth (slices)

__device__ __forceinline__ float f3(float a, float b, float c) {
    return fmaxf(fmaxf(a, b), c);
}

__global__ __launch_bounds__(256, 3)
void nms3d(const float* __restrict__ x, float* __restrict__ out)
{
    const int tx  = threadIdx.x;          // 0..63 lane
    const int ty  = threadIdx.y;          // 0..3 wave id
    const int bid = blockIdx.x;           // 0..767
    const int n    = bid & 7;             // volume == XCD
    const int rest = bid >> 3;            // 0..95
    const int rg   = rest & 15;           // row-group (16 rows / block)
    const int ck   = rest >> 4;           // z-chunk 0..5
    const int z0   = ck * DC;
    const int R0   = (rg << 4) + (ty << 2);   // wave's first output row
    const int c    = tx << 2;

    const float* __restrict__ base  = x   + (size_t)n * D_ * HW_;
    float* __restrict__       obase = out + (size_t)n * D_ * HW_;

    // element offsets of the 6 staged rows (h-clamped once)
    const int ro0 = max(R0 - 1, 0) * W_ + c;
    const int ro1 = (R0    ) * W_ + c;
    const int ro2 = (R0 + 1) * W_ + c;
    const int ro3 = (R0 + 2) * W_ + c;
    const int ro4 = (R0 + 3) * W_ + c;
    const int ro5 = min(R0 + 4, H_ - 1) * W_ + c;

    float4 wA[6], wB[6], wC[6];
    // per-row rolling state: vm9p = vmax9[z-1]; m2 = max(vmax9[z-2],cross8[z-1])
    float4 vm9p[4], m2[4], vprev[4];

#define LOADSET(WSET, SLICE) do {                                      \
        const int zc_ = min(max(z0 - 1 + (SLICE), 0), D_ - 1);         \
        const float* sp_ = base + (size_t)zc_ * HW_;                   \
        WSET[0] = *(const float4*)(sp_ + ro0);                         \
        WSET[1] = *(const float4*)(sp_ + ro1);                         \
        WSET[2] = *(const float4*)(sp_ + ro2);                         \
        WSET[3] = *(const float4*)(sp_ + ro3);                         \
        WSET[4] = *(const float4*)(sp_ + ro4);                         \
        WSET[5] = *(const float4*)(sp_ + ro5);                         \
    } while (0)

    LOADSET(wA, 0);
    LOADSET(wB, 1);
    LOADSET(wC, 2);

#pragma unroll
    for (int r = 0; r < 4; ++r) {
        vm9p[r]  = make_float4(0.f, 0.f, 0.f, 0.f);
        m2[r]    = make_float4(0.f, 0.f, 0.f, 0.f);
        vprev[r] = make_float4(0.f, 0.f, 0.f, 0.f);
    }

    // One slice step: compute on WCUR (slice T), emit out[z0+T-2], update
    // state, then reuse WCUR's registers to issue loads for slice T+PF.
#define STEP(T, WCUR) do {                                             \
        const int zo_ = z0 + (T) - 2;                                  \
        _Pragma("unroll")                                              \
        for (int r = 0; r < 4; ++r) {                                  \
            const float4 up = WCUR[r], dn = WCUR[r + 2], b0 = WCUR[r + 1]; \
            float4 va;                                                 \
            va.x = fmaxf(up.x, dn.x); va.y = fmaxf(up.y, dn.y);        \
            va.z = fmaxf(up.z, dn.z); va.w = fmaxf(up.w, dn.w);        \
            float vaL = __shfl_up(va.w, 1);   if (tx == 0)  vaL = va.x; \
            float vaR = __shfl_down(va.x, 1); if (tx == 63) vaR = va.w; \
            float bL  = __shfl_up(b0.w, 1);   if (tx == 0)  bL  = b0.x; \
            float bR  = __shfl_down(b0.x, 1); if (tx == 63) bR  = b0.w; \
            float4 hv, nb, c8, cur;                                    \
            hv.x = f3(vaL, va.x, va.y);  hv.y = f3(va.x, va.y, va.z);  \
            hv.z = f3(va.y, va.z, va.w); hv.w = f3(va.z, va.w, vaR);   \
            nb.x = fmaxf(bL,  b0.y);  nb.y = fmaxf(b0.x, b0.z);        \
            nb.z = fmaxf(b0.y, b0.w); nb.w = fmaxf(b0.z, bR);          \
            c8.x = fmaxf(hv.x, nb.x); c8.y = fmaxf(hv.y, nb.y);        \
            c8.z = fmaxf(hv.z, nb.z); c8.w = fmaxf(hv.w, nb.w);        \
            cur.x = fmaxf(c8.x, b0.x); cur.y = fmaxf(c8.y, b0.y);      \
            cur.z = fmaxf(c8.z, b0.z); cur.w = fmaxf(c8.w, b0.w);      \
            if ((T) >= 2 && zo_ < D_) {                                \
                float4 mx, o;                                          \
                mx.x = fmaxf(m2[r].x, cur.x);                          \
                mx.y = fmaxf(m2[r].y, cur.y);                          \
                mx.z = fmaxf(m2[r].z, cur.z);                          \
                mx.w = fmaxf(m2[r].w, cur.w);                          \
                o.x = vprev[r].x > mx.x ? vprev[r].x : 0.0f;           \
                o.y = vprev[r].y > mx.y ? vprev[r].y : 0.0f;           \
                o.z = vprev[r].z > mx.z ? vprev[r].z : 0.0f;           \
                o.w = vprev[r].w > mx.w ? vprev[r].w : 0.0f;           \
                *(float4*)(obase + (size_t)zo_ * HW_ +                 \
                           (size_t)(R0 + r) * W_ + c) = o;             \
            }                                                          \
            float4 t2;                                                 \
            t2.x = fmaxf(vm9p[r].x, c8.x);                             \
            t2.y = fmaxf(vm9p[r].y, c8.y);                             \
            t2.z = fmaxf(vm9p[r].z, c8.z);                             \
            t2.w = fmaxf(vm9p[r].w, c8.w);                             \
            m2[r] = t2; vm9p[r] = cur; vprev[r] = b0;                  \
        }                                                              \
        if ((T) + PF < S) LOADSET(WCUR, (T) + PF);                     \
    } while (0)

    STEP(0,  wA); STEP(1,  wB); STEP(2,  wC);
    STEP(3,  wA); STEP(4,  wB); STEP(5,  wC);
    STEP(6,  wA); STEP(7,  wB); STEP(8,  wC);
    STEP(9,  wA); STEP(10, wB); STEP(11, wC);
    STEP(12, wA);

#undef STEP
#undef LOADSET
}

extern "C" void kernel_launch(void* const* d_in, const int* in_sizes, int n_in,
                              void* d_out, int out_size, void* d_ws, size_t ws_size,
                              hipStream_t stream)
{
    const float* x = (const float*)d_in[0];
    float* out = (float*)d_out;
    dim3 block(64, 4, 1);                  // 4 waves; wave = 4 output rows
    dim3 grid(8 * 16 * 6, 1, 1);           // vol x rowgroup x zchunk = 768
    nms3d<<<grid, block, 0, stream>>>(x, out);
}